// Round 7
// baseline (354.744 us; speedup 1.0000x reference)
//
#include <hip/hip_runtime.h>
#include <stdint.h>

// ROUND 7 = DIAGNOSTIC ROUND. Kernels are byte-identical to round 6.
// k_qk is launched 3x (idempotent): dur_r7 - dur_r6 = 2 * t(k_qk).
// This isolates per-kernel time, which the fill-polluted top-5 hides.

// ---------- types ----------
typedef __bf16 bf16x8 __attribute__((ext_vector_type(8)));
typedef unsigned short u16x8 __attribute__((ext_vector_type(8)));
typedef float f32x4 __attribute__((ext_vector_type(4)));

#define SM_SCALE 4.419417382415922e-02f /* 1/22.627416997969522 */
#define DROP_SCALE (1.0f / 0.9f)

// ---------- helpers ----------
__device__ __forceinline__ unsigned short f2bf(float f) {
  uint32_t u = __float_as_uint(f);
  uint32_t r = (u + 0x7FFFu + ((u >> 16) & 1u)) >> 16;  // RNE
  return (unsigned short)r;
}
__device__ __forceinline__ float bf2f(unsigned short h) {
  return __uint_as_float(((uint32_t)h) << 16);
}

// async global->LDS, 16B/lane. LDS dest = wave-uniform base + lane*16.
__device__ __forceinline__ void async16(const void* g, void* l) {
  __builtin_amdgcn_global_load_lds(
      (__attribute__((address_space(1))) uint32_t*)g,
      (__attribute__((address_space(3))) uint32_t*)l, 16, 0, 0);
}

// JAX threefry2x32 with key (0,42). [validated r4]
__device__ __forceinline__ void threefry2x32(uint32_t x0, uint32_t x1,
                                             uint32_t& o0, uint32_t& o1) {
  const uint32_t K0 = 0u, K1 = 42u;
  const uint32_t K2 = K0 ^ K1 ^ 0x1BD11BDAu;
  x0 += K0; x1 += K1;
#define TF_R(rot) { x0 += x1; x1 = (x1 << rot) | (x1 >> (32 - rot)); x1 ^= x0; }
  TF_R(13) TF_R(15) TF_R(26) TF_R(6)  x0 += K1; x1 += K2 + 1u;
  TF_R(17) TF_R(29) TF_R(16) TF_R(24) x0 += K2; x1 += K0 + 2u;
  TF_R(13) TF_R(15) TF_R(26) TF_R(6)  x0 += K0; x1 += K1 + 3u;
  TF_R(17) TF_R(29) TF_R(16) TF_R(24) x0 += K1; x1 += K2 + 4u;
  TF_R(13) TF_R(15) TF_R(26) TF_R(6)  x0 += K2; x1 += K0 + 5u;
#undef TF_R
  o0 = x0; o1 = x1;
}

// keep-mask, JAX partitionable threefry, ctr=(0,idx), XOR-fold. [validated r4]
__device__ __forceinline__ bool drop_keep(uint32_t idx) {
  uint32_t o0, o1;
  threefry2x32(0u, idx, o0, o1);
  uint32_t bits = o0 ^ o1;
  float u = __uint_as_float((bits >> 9) | 0x3f800000u) - 1.0f;  // [0,1)
  return u < 0.9f;
}

// ---------- kernel 1: value[512][4096] f32 -> valueT[4096][512] bf16 [validated r4] ----
__global__ __launch_bounds__(256) void k_vt(const float* __restrict__ v,
                                            unsigned short* __restrict__ vt) {
  __shared__ float tile[32][33];
  const int nb = blockIdx.x;   // 0..127
  const int kb = blockIdx.y;   // 0..15
  const int tx = threadIdx.x & 31, ty = threadIdx.x >> 5;  // 32 x 8
#pragma unroll
  for (int yy = 0; yy < 4; ++yy) {
    int row = ty + yy * 8;
    tile[row][tx] = v[(size_t)(kb * 32 + row) * 4096 + nb * 32 + tx];
  }
  __syncthreads();
#pragma unroll
  for (int yy = 0; yy < 4; ++yy) {
    int row = ty + yy * 8;
    vt[(size_t)(nb * 32 + row) * 512 + kb * 32 + tx] = f2bf(tile[tx][row]);
  }
}

// ---------- kernel 1b: in2 f32 -> bf16 hi/lo split [validated r5] ----------
__global__ __launch_bounds__(256) void k_split(const float* __restrict__ src,
                                               unsigned short* __restrict__ hi,
                                               unsigned short* __restrict__ lo,
                                               int n4) {
  int i = blockIdx.x * 256 + threadIdx.x;
  if (i >= n4) return;
  float4 v = reinterpret_cast<const float4*>(src)[i];
  ushort4 h, l;
  h.x = f2bf(v.x); l.x = f2bf(v.x - bf2f(h.x));
  h.y = f2bf(v.y); l.y = f2bf(v.y - bf2f(h.y));
  h.z = f2bf(v.z); l.z = f2bf(v.z - bf2f(h.z));
  h.w = f2bf(v.w); l.w = f2bf(v.w - bf2f(h.w));
  reinterpret_cast<ushort4*>(hi)[i] = h;
  reinterpret_cast<ushort4*>(lo)[i] = l;
}

// ---------- kernel 2: QK^T (split-bf16 MFMA) + softmax + dropout -> P bf16 ----------
// [byte-identical to r6]
__global__ __launch_bounds__(512) void k_qk(const float* __restrict__ in1,
                                            const unsigned short* __restrict__ B2hi,
                                            const unsigned short* __restrict__ B2lo,
                                            unsigned short* __restrict__ P) {
  __shared__ unsigned short lB[512][72];  // [col][hi 0..31 | lo 32..63 | pad] 73.7KB
  __shared__ float redm[4][32], reds[4][32];

  const int tid = threadIdx.x;
  const int l = tid & 63, w = tid >> 6;
  const int wr = w >> 2, wc = w & 3;      // wave grid 2 x 4
  const int g = l >> 4, c16 = l & 15;
  const int brow = blockIdx.x * 32;

  f32x4 acc[8] = {};

  for (int kt = 0; kt < 16; ++kt) {
    const int k0 = kt * 32;
    // ---- stage B hi+lo tile [512 cols][32 k] each ----
#pragma unroll
    for (int i = 0; i < 8; ++i) {
      int c = i * 512 + tid;                // 4096 chunks of 8 shorts
      int col = c >> 3, half = (c >> 2) & 1, sub = c & 3;
      const unsigned short* src = (half ? B2lo : B2hi) + (size_t)col * 512 + k0 + sub * 8;
      *reinterpret_cast<u16x8*>(&lB[col][half * 32 + sub * 8]) =
          *reinterpret_cast<const u16x8*>(src);
    }
    // ---- A fragment direct from global, split in-register ----
    const int arow = brow + wr * 16 + c16;
    float4 v0 = *reinterpret_cast<const float4*>(in1 + (size_t)arow * 512 + k0 + g * 8);
    float4 v1 = *reinterpret_cast<const float4*>(in1 + (size_t)arow * 512 + k0 + g * 8 + 4);
    bf16x8 ahi, alo;
    {
      float vv[8] = {v0.x, v0.y, v0.z, v0.w, v1.x, v1.y, v1.z, v1.w};
      unsigned short h[8], lo8[8];
#pragma unroll
      for (int e = 0; e < 8; ++e) {
        h[e] = f2bf(vv[e]);
        lo8[e] = f2bf(vv[e] - bf2f(h[e]));
      }
      ahi = *reinterpret_cast<const bf16x8*>(h);
      alo = *reinterpret_cast<const bf16x8*>(lo8);
    }
    __syncthreads();
#pragma unroll
    for (int j = 0; j < 8; ++j) {
      const int col = wc * 128 + j * 16 + c16;
      bf16x8 bh = *reinterpret_cast<const bf16x8*>(&lB[col][g * 8]);
      bf16x8 bl = *reinterpret_cast<const bf16x8*>(&lB[col][32 + g * 8]);
      acc[j] = __builtin_amdgcn_mfma_f32_16x16x32_bf16(ahi, bh, acc[j], 0, 0, 0);
      acc[j] = __builtin_amdgcn_mfma_f32_16x16x32_bf16(alo, bh, acc[j], 0, 0, 0);
      acc[j] = __builtin_amdgcn_mfma_f32_16x16x32_bf16(ahi, bl, acc[j], 0, 0, 0);
    }
    __syncthreads();
  }

  // ---- epilogue: scale, softmax over 512 cols, dropout, write P bf16 ----
  const int rowbase = wr * 16 + g * 4;
  float mx[4] = {-3.4e38f, -3.4e38f, -3.4e38f, -3.4e38f};
#pragma unroll
  for (int j = 0; j < 8; ++j)
#pragma unroll
    for (int r = 0; r < 4; ++r) {
      acc[j][r] *= SM_SCALE;
      mx[r] = fmaxf(mx[r], acc[j][r]);
    }
#pragma unroll
  for (int s = 1; s < 16; s <<= 1)
#pragma unroll
    for (int r = 0; r < 4; ++r) mx[r] = fmaxf(mx[r], __shfl_xor(mx[r], s, 64));
  if (c16 == 0) {
#pragma unroll
    for (int r = 0; r < 4; ++r) redm[wc][rowbase + r] = mx[r];
  }
  __syncthreads();
  float rmax[4], sum[4] = {0.f, 0.f, 0.f, 0.f};
#pragma unroll
  for (int r = 0; r < 4; ++r)
    rmax[r] = fmaxf(fmaxf(redm[0][rowbase + r], redm[1][rowbase + r]),
                    fmaxf(redm[2][rowbase + r], redm[3][rowbase + r]));
#pragma unroll
  for (int j = 0; j < 8; ++j)
#pragma unroll
    for (int r = 0; r < 4; ++r) {
      float e = expf(acc[j][r] - rmax[r]);
      acc[j][r] = e;
      sum[r] += e;
    }
#pragma unroll
  for (int s = 1; s < 16; s <<= 1)
#pragma unroll
    for (int r = 0; r < 4; ++r) sum[r] += __shfl_xor(sum[r], s, 64);
  if (c16 == 0) {
#pragma unroll
    for (int r = 0; r < 4; ++r) reds[wc][rowbase + r] = sum[r];
  }
  __syncthreads();
  float scl[4];
#pragma unroll
  for (int r = 0; r < 4; ++r)
    scl[r] = DROP_SCALE / (reds[0][rowbase + r] + reds[1][rowbase + r] +
                           reds[2][rowbase + r] + reds[3][rowbase + r]);

#pragma unroll
  for (int j = 0; j < 8; ++j) {
    const int col = wc * 128 + j * 16 + c16;
#pragma unroll
    for (int r = 0; r < 4; ++r) {
      uint32_t idx = (uint32_t)(brow + rowbase + r) * 512u + (uint32_t)col;
      float pv = drop_keep(idx) ? acc[j][r] * scl[r] : 0.0f;
      P[idx] = f2bf(pv);
    }
  }
}

// ---------- kernel 3: out = P[16384][512] @ vT[4096][512]^T [byte-identical to r6] ----
__global__ __launch_bounds__(256) void k_pv(const unsigned short* __restrict__ P,
                                            const unsigned short* __restrict__ VT,
                                            float* __restrict__ out) {
  __shared__ unsigned short lA[128][64];  // linear, no pad (gload_lds dest)
  __shared__ unsigned short lB[128][64];
  const int tid = threadIdx.x;
  const int l = tid & 63, w = tid >> 6;
  const int wr = w >> 1, wc = w & 1;
  const int g = l >> 4, c16 = l & 15;

  const int bid = blockIdx.x;
  const int x = (bid & 7) * 512 + (bid >> 3);  // XCD-aware, bijective (4096%8==0)
  const int brow = (x >> 5) * 128;
  const int bcol = (x & 31) * 128;

  f32x4 acc[4][4] = {};

  for (int kt = 0; kt < 8; ++kt) {
    const int k0 = kt * 64;
#pragma unroll
    for (int i = 0; i < 4; ++i) {
      int c = i * 256 + tid;                 // 1024 chunks of 16B per matrix
      int row = c >> 3, slot = c & 7;
      int gsub = slot ^ (row & 7);           // inverse-swizzled source
      async16(P + (size_t)(brow + row) * 512 + k0 + gsub * 8,
              lA[0] + (size_t)(i * 256 + w * 64) * 8);
      async16(VT + (size_t)(bcol + row) * 512 + k0 + gsub * 8,
              lB[0] + (size_t)(i * 256 + w * 64) * 8);
    }
    asm volatile("s_waitcnt vmcnt(0)" ::: "memory");
    __syncthreads();

#pragma unroll
    for (int kk = 0; kk < 64; kk += 32) {
      bf16x8 a[4], b[4];
#pragma unroll
      for (int i = 0; i < 4; ++i) {
        int row = wr * 64 + i * 16 + c16;
        int s = ((kk >> 3) + g) ^ (row & 7);  // swizzled ds_read slot
        a[i] = *reinterpret_cast<const bf16x8*>(&lA[row][s * 8]);
      }
#pragma unroll
      for (int j = 0; j < 4; ++j) {
        int row = wc * 64 + j * 16 + c16;
        int s = ((kk >> 3) + g) ^ (row & 7);
        b[j] = *reinterpret_cast<const bf16x8*>(&lB[row][s * 8]);
      }
#pragma unroll
      for (int i = 0; i < 4; ++i)
#pragma unroll
        for (int j = 0; j < 4; ++j)
          acc[i][j] = __builtin_amdgcn_mfma_f32_16x16x32_bf16(a[i], b[j], acc[i][j], 0, 0, 0);
    }
    __syncthreads();
  }

  // C/D layout (validated r4): col = lane&15, row = (lane>>4)*4 + reg
#pragma unroll
  for (int i = 0; i < 4; ++i)
#pragma unroll
    for (int r = 0; r < 4; ++r) {
      const size_t row = (size_t)(brow + wr * 64 + i * 16 + g * 4 + r);
      float* o = out + row * 4096 + bcol + wc * 64 + c16;
#pragma unroll
      for (int j = 0; j < 4; ++j) o[j * 16] = acc[i][j][r];
    }
}

// ---------- launch ----------
extern "C" void kernel_launch(void* const* d_in, const int* in_sizes, int n_in,
                              void* d_out, int out_size, void* d_ws, size_t ws_size,
                              hipStream_t stream) {
  (void)in_sizes; (void)n_in; (void)out_size; (void)ws_size;
  const float* in1   = (const float*)d_in[0];   // [16384][512]
  const float* in2   = (const float*)d_in[1];   // [512][512]
  const float* value = (const float*)d_in[2];   // [512][4096]
  float* out = (float*)d_out;                   // [16384][4096]

  unsigned short* vT    = (unsigned short*)d_ws;  // 4 MB   [4096][512] bf16
  unsigned short* Pb    = vT + 2097152;           // 16 MB  [16384][512] bf16
  unsigned short* in2hi = Pb + 8388608;           // 0.5 MB [512][512] bf16
  unsigned short* in2lo = in2hi + 262144;         // 0.5 MB

  k_vt<<<dim3(128, 16), dim3(256), 0, stream>>>(value, vT);
  k_split<<<dim3(256), dim3(256), 0, stream>>>(in2, in2hi, in2lo, 65536);
  // DIAGNOSTIC: k_qk launched 3x (idempotent, deterministic).
  // dur_r7 - dur_r6 = 2 * t(k_qk).
  k_qk<<<dim3(512), dim3(512), 0, stream>>>(in1, in2hi, in2lo, Pb);
  k_qk<<<dim3(512), dim3(512), 0, stream>>>(in1, in2hi, in2lo, Pb);
  k_qk<<<dim3(512), dim3(512), 0, stream>>>(in1, in2hi, in2lo, Pb);
  k_pv<<<dim3(4096), dim3(256), 0, stream>>>(Pb, vT, out);
}

// Round 8
// 206.241 us; speedup vs baseline: 1.7200x; 1.7200x over previous
//
#include <hip/hip_runtime.h>
#include <stdint.h>

// r8: k_pv reverted to r4 reg-staged bytes (measured 60us; gload_lds+src-swizzle
// variant measured 119us in r6/r7 ledger — swizzled source defeats coalescer).
// k_qk: 64 rows/block, 256 blocks — 2x MFMA per barrier, half B-staging traffic.

// ---------- types ----------
typedef __bf16 bf16x8 __attribute__((ext_vector_type(8)));
typedef unsigned short u16x8 __attribute__((ext_vector_type(8)));
typedef float f32x4 __attribute__((ext_vector_type(4)));

#define SM_SCALE 4.419417382415922e-02f /* 1/22.627416997969522 */
#define DROP_SCALE (1.0f / 0.9f)

// ---------- helpers ----------
__device__ __forceinline__ unsigned short f2bf(float f) {
  uint32_t u = __float_as_uint(f);
  uint32_t r = (u + 0x7FFFu + ((u >> 16) & 1u)) >> 16;  // RNE
  return (unsigned short)r;
}
__device__ __forceinline__ float bf2f(unsigned short h) {
  return __uint_as_float(((uint32_t)h) << 16);
}

// JAX threefry2x32 with key (0,42). [validated r4]
__device__ __forceinline__ void threefry2x32(uint32_t x0, uint32_t x1,
                                             uint32_t& o0, uint32_t& o1) {
  const uint32_t K0 = 0u, K1 = 42u;
  const uint32_t K2 = K0 ^ K1 ^ 0x1BD11BDAu;
  x0 += K0; x1 += K1;
#define TF_R(rot) { x0 += x1; x1 = (x1 << rot) | (x1 >> (32 - rot)); x1 ^= x0; }
  TF_R(13) TF_R(15) TF_R(26) TF_R(6)  x0 += K1; x1 += K2 + 1u;
  TF_R(17) TF_R(29) TF_R(16) TF_R(24) x0 += K2; x1 += K0 + 2u;
  TF_R(13) TF_R(15) TF_R(26) TF_R(6)  x0 += K0; x1 += K1 + 3u;
  TF_R(17) TF_R(29) TF_R(16) TF_R(24) x0 += K1; x1 += K2 + 4u;
  TF_R(13) TF_R(15) TF_R(26) TF_R(6)  x0 += K2; x1 += K0 + 5u;
#undef TF_R
  o0 = x0; o1 = x1;
}

// keep-mask, JAX partitionable threefry, ctr=(0,idx), XOR-fold. [validated r4]
__device__ __forceinline__ bool drop_keep(uint32_t idx) {
  uint32_t o0, o1;
  threefry2x32(0u, idx, o0, o1);
  uint32_t bits = o0 ^ o1;
  float u = __uint_as_float((bits >> 9) | 0x3f800000u) - 1.0f;  // [0,1)
  return u < 0.9f;
}

// ---------- kernel 1: value[512][4096] f32 -> valueT[4096][512] bf16 [validated r4] ----
__global__ __launch_bounds__(256) void k_vt(const float* __restrict__ v,
                                            unsigned short* __restrict__ vt) {
  __shared__ float tile[32][33];
  const int nb = blockIdx.x;   // 0..127
  const int kb = blockIdx.y;   // 0..15
  const int tx = threadIdx.x & 31, ty = threadIdx.x >> 5;  // 32 x 8
#pragma unroll
  for (int yy = 0; yy < 4; ++yy) {
    int row = ty + yy * 8;
    tile[row][tx] = v[(size_t)(kb * 32 + row) * 4096 + nb * 32 + tx];
  }
  __syncthreads();
#pragma unroll
  for (int yy = 0; yy < 4; ++yy) {
    int row = ty + yy * 8;
    vt[(size_t)(nb * 32 + row) * 512 + kb * 32 + tx] = f2bf(tile[tx][row]);
  }
}

// ---------- kernel 1b: in2 f32 -> bf16 hi/lo split [validated r5] ----------
__global__ __launch_bounds__(256) void k_split(const float* __restrict__ src,
                                               unsigned short* __restrict__ hi,
                                               unsigned short* __restrict__ lo,
                                               int n4) {
  int i = blockIdx.x * 256 + threadIdx.x;
  if (i >= n4) return;
  float4 v = reinterpret_cast<const float4*>(src)[i];
  ushort4 h, l;
  h.x = f2bf(v.x); l.x = f2bf(v.x - bf2f(h.x));
  h.y = f2bf(v.y); l.y = f2bf(v.y - bf2f(h.y));
  h.z = f2bf(v.z); l.z = f2bf(v.z - bf2f(h.z));
  h.w = f2bf(v.w); l.w = f2bf(v.w - bf2f(h.w));
  reinterpret_cast<ushort4*>(hi)[i] = h;
  reinterpret_cast<ushort4*>(lo)[i] = l;
}

// ---------- kernel 2: QK^T (split-bf16 MFMA) + softmax + dropout -> P bf16 ----------
// v3: 256 blocks x 512 thr (8 waves, 4 row-groups x 2 col-halves), 64 rows x 512 cols.
// B hi+lo staged together per K-tile (r6-validated staging); A direct from global
// with in-register hi/lo split (r6-validated); r5-validated 64-row epilogue.
__global__ __launch_bounds__(512) void k_qk(const float* __restrict__ in1,
                                            const unsigned short* __restrict__ B2hi,
                                            const unsigned short* __restrict__ B2lo,
                                            unsigned short* __restrict__ P) {
  __shared__ unsigned short lB[512][72];  // [col][hi 0..31 | lo 32..63 | pad] 73.7KB
  __shared__ float redm[2][64], reds[2][64];

  const int tid = threadIdx.x;
  const int l = tid & 63, w = tid >> 6;
  const int wr = w >> 1, wc = w & 1;      // wave grid 4 x 2
  const int g = l >> 4, c16 = l & 15;
  const int brow = blockIdx.x * 64;

  f32x4 acc[16] = {};

  for (int kt = 0; kt < 16; ++kt) {
    const int k0 = kt * 32;
    // ---- stage B hi+lo tile [512 cols][32 k each] ----
#pragma unroll
    for (int i = 0; i < 8; ++i) {
      int c = i * 512 + tid;                // 4096 chunks of 8 shorts
      int col = c >> 3, half = (c >> 2) & 1, sub = c & 3;
      const unsigned short* src = (half ? B2lo : B2hi) + (size_t)col * 512 + k0 + sub * 8;
      *reinterpret_cast<u16x8*>(&lB[col][half * 32 + sub * 8]) =
          *reinterpret_cast<const u16x8*>(src);
    }
    // ---- A fragment direct from global, split in-register ----
    const int arow = brow + wr * 16 + c16;
    float4 v0 = *reinterpret_cast<const float4*>(in1 + (size_t)arow * 512 + k0 + g * 8);
    float4 v1 = *reinterpret_cast<const float4*>(in1 + (size_t)arow * 512 + k0 + g * 8 + 4);
    bf16x8 ahi, alo;
    {
      float vv[8] = {v0.x, v0.y, v0.z, v0.w, v1.x, v1.y, v1.z, v1.w};
      unsigned short h[8], lo8[8];
#pragma unroll
      for (int e = 0; e < 8; ++e) {
        h[e] = f2bf(vv[e]);
        lo8[e] = f2bf(vv[e] - bf2f(h[e]));
      }
      ahi = *reinterpret_cast<const bf16x8*>(h);
      alo = *reinterpret_cast<const bf16x8*>(lo8);
    }
    __syncthreads();
#pragma unroll
    for (int j = 0; j < 16; ++j) {
      const int col = wc * 256 + j * 16 + c16;
      bf16x8 bh = *reinterpret_cast<const bf16x8*>(&lB[col][g * 8]);
      bf16x8 bl = *reinterpret_cast<const bf16x8*>(&lB[col][32 + g * 8]);
      acc[j] = __builtin_amdgcn_mfma_f32_16x16x32_bf16(ahi, bh, acc[j], 0, 0, 0);
      acc[j] = __builtin_amdgcn_mfma_f32_16x16x32_bf16(alo, bh, acc[j], 0, 0, 0);
      acc[j] = __builtin_amdgcn_mfma_f32_16x16x32_bf16(ahi, bl, acc[j], 0, 0, 0);
    }
    __syncthreads();
  }

  // ---- epilogue: scale, softmax over 512 cols, dropout, write P bf16 [r5-validated] ----
  // C/D layout: col = c16 (+j*16+wc*256), row = g*4 + r (+wr*16)
  const int rowbase = wr * 16 + g * 4;
  float mx[4] = {-3.4e38f, -3.4e38f, -3.4e38f, -3.4e38f};
#pragma unroll
  for (int j = 0; j < 16; ++j)
#pragma unroll
    for (int r = 0; r < 4; ++r) {
      acc[j][r] *= SM_SCALE;
      mx[r] = fmaxf(mx[r], acc[j][r]);
    }
#pragma unroll
  for (int s = 1; s < 16; s <<= 1)
#pragma unroll
    for (int r = 0; r < 4; ++r) mx[r] = fmaxf(mx[r], __shfl_xor(mx[r], s, 64));
  if (c16 == 0) {
#pragma unroll
    for (int r = 0; r < 4; ++r) redm[wc][rowbase + r] = mx[r];
  }
  __syncthreads();
  float rmax[4], sum[4] = {0.f, 0.f, 0.f, 0.f};
#pragma unroll
  for (int r = 0; r < 4; ++r)
    rmax[r] = fmaxf(redm[0][rowbase + r], redm[1][rowbase + r]);
#pragma unroll
  for (int j = 0; j < 16; ++j)
#pragma unroll
    for (int r = 0; r < 4; ++r) {
      float e = expf(acc[j][r] - rmax[r]);
      acc[j][r] = e;
      sum[r] += e;
    }
#pragma unroll
  for (int s = 1; s < 16; s <<= 1)
#pragma unroll
    for (int r = 0; r < 4; ++r) sum[r] += __shfl_xor(sum[r], s, 64);
  if (c16 == 0) {
#pragma unroll
    for (int r = 0; r < 4; ++r) reds[wc][rowbase + r] = sum[r];
  }
  __syncthreads();
  float scl[4];
#pragma unroll
  for (int r = 0; r < 4; ++r)
    scl[r] = DROP_SCALE / (reds[0][rowbase + r] + reds[1][rowbase + r]);

#pragma unroll
  for (int j = 0; j < 16; ++j) {
    const int col = wc * 256 + j * 16 + c16;
#pragma unroll
    for (int r = 0; r < 4; ++r) {
      uint32_t idx = (uint32_t)(brow + rowbase + r) * 512u + (uint32_t)col;
      float pv = drop_keep(idx) ? acc[j][r] * scl[r] : 0.0f;
      P[idx] = f2bf(pv);
    }
  }
}

// ---------- kernel 3: out = P[16384][512] @ vT[4096][512]^T (bf16 MFMA) ----------
// [r4 bytes, reg-staged LDS +8 pad — measured 60us, validated]
__global__ __launch_bounds__(256) void k_pv(const unsigned short* __restrict__ P,
                                            const unsigned short* __restrict__ VT,
                                            float* __restrict__ out) {
  __shared__ unsigned short lA[128][72];  // 72 = 64 + 8 pad (16B-aligned rows)
  __shared__ unsigned short lB[128][72];
  const int tid = threadIdx.x;
  const int l = tid & 63, w = tid >> 6;
  const int wr = w >> 1, wc = w & 1;
  const int g = l >> 4, c16 = l & 15;

  // XCD-aware bijective swizzle (4096 % 8 == 0)
  const int bid = blockIdx.x;
  const int x = (bid & 7) * 512 + (bid >> 3);
  const int brow = (x >> 5) * 128;   // 128 row-tiles
  const int bcol = (x & 31) * 128;   // 32 col-tiles

  f32x4 acc[4][4] = {};

  for (int kt = 0; kt < 8; ++kt) {
    const int k0 = kt * 64;
#pragma unroll
    for (int i = 0; i < 4; ++i) {
      int c = i * 256 + tid;          // 0..1023 chunks of 8 shorts
      int row = c >> 3, sub = c & 7;
      u16x8 va = *reinterpret_cast<const u16x8*>(
          P + (size_t)(brow + row) * 512 + k0 + sub * 8);
      u16x8 vb = *reinterpret_cast<const u16x8*>(
          VT + (size_t)(bcol + row) * 512 + k0 + sub * 8);
      *reinterpret_cast<u16x8*>(&lA[row][sub * 8]) = va;
      *reinterpret_cast<u16x8*>(&lB[row][sub * 8]) = vb;
    }
    __syncthreads();

#pragma unroll
    for (int kk = 0; kk < 64; kk += 32) {
      bf16x8 a[4], b[4];
#pragma unroll
      for (int i = 0; i < 4; ++i)
        a[i] = *reinterpret_cast<const bf16x8*>(&lA[wr * 64 + i * 16 + c16][kk + g * 8]);
#pragma unroll
      for (int j = 0; j < 4; ++j)
        b[j] = *reinterpret_cast<const bf16x8*>(&lB[wc * 64 + j * 16 + c16][kk + g * 8]);
#pragma unroll
      for (int i = 0; i < 4; ++i)
#pragma unroll
        for (int j = 0; j < 4; ++j)
          acc[i][j] = __builtin_amdgcn_mfma_f32_16x16x32_bf16(a[i], b[j], acc[i][j], 0, 0, 0);
    }
    __syncthreads();
  }

  // C/D layout (validated r4): col = lane&15, row = (lane>>4)*4 + reg
#pragma unroll
  for (int i = 0; i < 4; ++i)
#pragma unroll
    for (int r = 0; r < 4; ++r) {
      const size_t row = (size_t)(brow + wr * 64 + i * 16 + g * 4 + r);
      float* o = out + row * 4096 + bcol + wc * 64 + c16;
#pragma unroll
      for (int j = 0; j < 4; ++j) o[j * 16] = acc[i][j][r];
    }
}

// ---------- launch ----------
extern "C" void kernel_launch(void* const* d_in, const int* in_sizes, int n_in,
                              void* d_out, int out_size, void* d_ws, size_t ws_size,
                              hipStream_t stream) {
  (void)in_sizes; (void)n_in; (void)out_size; (void)ws_size;
  const float* in1   = (const float*)d_in[0];   // [16384][512]
  const float* in2   = (const float*)d_in[1];   // [512][512]
  const float* value = (const float*)d_in[2];   // [512][4096]
  float* out = (float*)d_out;                   // [16384][4096]

  unsigned short* vT    = (unsigned short*)d_ws;  // 4 MB   [4096][512] bf16
  unsigned short* Pb    = vT + 2097152;           // 16 MB  [16384][512] bf16
  unsigned short* in2hi = Pb + 8388608;           // 0.5 MB [512][512] bf16
  unsigned short* in2lo = in2hi + 262144;         // 0.5 MB

  k_vt<<<dim3(128, 16), dim3(256), 0, stream>>>(value, vT);
  k_split<<<dim3(256), dim3(256), 0, stream>>>(in2, in2hi, in2lo, 65536);
  k_qk<<<dim3(256), dim3(512), 0, stream>>>(in1, in2hi, in2lo, Pb);
  k_pv<<<dim3(4096), dim3(256), 0, stream>>>(Pb, vT, out);
}

// Round 9
// 187.981 us; speedup vs baseline: 1.8871x; 1.0971x over previous
//
#include <hip/hip_runtime.h>
#include <stdint.h>

// r9: k_qk v4 = v2 geometry (32 rows/block, 512 blocks — measured 76.5us at
// 2 blocks/CU) + 2-term split (drop B-lo; halves staging, LDS 73.7->36.9KB)
// + __launch_bounds__(512,6) -> 3 blocks/CU. k_pv untouched (r4 bytes, 60us).
// Ledger: qk_v4 = dur_total - 66.

// ---------- types ----------
typedef __bf16 bf16x8 __attribute__((ext_vector_type(8)));
typedef unsigned short u16x8 __attribute__((ext_vector_type(8)));
typedef float f32x4 __attribute__((ext_vector_type(4)));

#define SM_SCALE 4.419417382415922e-02f /* 1/22.627416997969522 */
#define DROP_SCALE (1.0f / 0.9f)

// ---------- helpers ----------
__device__ __forceinline__ unsigned short f2bf(float f) {
  uint32_t u = __float_as_uint(f);
  uint32_t r = (u + 0x7FFFu + ((u >> 16) & 1u)) >> 16;  // RNE
  return (unsigned short)r;
}
__device__ __forceinline__ float bf2f(unsigned short h) {
  return __uint_as_float(((uint32_t)h) << 16);
}

// JAX threefry2x32 with key (0,42). [validated r4]
__device__ __forceinline__ void threefry2x32(uint32_t x0, uint32_t x1,
                                             uint32_t& o0, uint32_t& o1) {
  const uint32_t K0 = 0u, K1 = 42u;
  const uint32_t K2 = K0 ^ K1 ^ 0x1BD11BDAu;
  x0 += K0; x1 += K1;
#define TF_R(rot) { x0 += x1; x1 = (x1 << rot) | (x1 >> (32 - rot)); x1 ^= x0; }
  TF_R(13) TF_R(15) TF_R(26) TF_R(6)  x0 += K1; x1 += K2 + 1u;
  TF_R(17) TF_R(29) TF_R(16) TF_R(24) x0 += K2; x1 += K0 + 2u;
  TF_R(13) TF_R(15) TF_R(26) TF_R(6)  x0 += K0; x1 += K1 + 3u;
  TF_R(17) TF_R(29) TF_R(16) TF_R(24) x0 += K1; x1 += K2 + 4u;
  TF_R(13) TF_R(15) TF_R(26) TF_R(6)  x0 += K2; x1 += K0 + 5u;
#undef TF_R
  o0 = x0; o1 = x1;
}

// keep-mask, JAX partitionable threefry, ctr=(0,idx), XOR-fold. [validated r4]
__device__ __forceinline__ bool drop_keep(uint32_t idx) {
  uint32_t o0, o1;
  threefry2x32(0u, idx, o0, o1);
  uint32_t bits = o0 ^ o1;
  float u = __uint_as_float((bits >> 9) | 0x3f800000u) - 1.0f;  // [0,1)
  return u < 0.9f;
}

// ---------- kernel 1: value[512][4096] f32 -> valueT[4096][512] bf16 [validated r4] ----
__global__ __launch_bounds__(256) void k_vt(const float* __restrict__ v,
                                            unsigned short* __restrict__ vt) {
  __shared__ float tile[32][33];
  const int nb = blockIdx.x;   // 0..127
  const int kb = blockIdx.y;   // 0..15
  const int tx = threadIdx.x & 31, ty = threadIdx.x >> 5;  // 32 x 8
#pragma unroll
  for (int yy = 0; yy < 4; ++yy) {
    int row = ty + yy * 8;
    tile[row][tx] = v[(size_t)(kb * 32 + row) * 4096 + nb * 32 + tx];
  }
  __syncthreads();
#pragma unroll
  for (int yy = 0; yy < 4; ++yy) {
    int row = ty + yy * 8;
    vt[(size_t)(nb * 32 + row) * 512 + kb * 32 + tx] = f2bf(tile[tx][row]);
  }
}

// ---------- kernel 1b: in2 f32 -> bf16 (RNE) ----------
__global__ __launch_bounds__(256) void k_cast(const float* __restrict__ src,
                                              unsigned short* __restrict__ dst,
                                              int n4) {
  int i = blockIdx.x * 256 + threadIdx.x;
  if (i >= n4) return;
  float4 v = reinterpret_cast<const float4*>(src)[i];
  ushort4 h;
  h.x = f2bf(v.x); h.y = f2bf(v.y); h.z = f2bf(v.z); h.w = f2bf(v.w);
  reinterpret_cast<ushort4*>(dst)[i] = h;
}

// ---------- kernel 2: QK^T (A-split bf16 MFMA) + softmax + dropout -> P bf16 ----------
// v4: 512 blocks x 512 thr (8 waves, 2 row-groups x 4 col-quarters), 32 rows/block.
// 2-term: ahi*bhi + alo*bhi (B-lo dropped; err sigma ~8e-4/logit, softmax-damped).
// LDS 36.9KB + launch_bounds(512,6) -> 3 blocks/CU (v2 measured: time ~ 1/(blocks/CU)).
__global__ __launch_bounds__(512, 6) void k_qk(const float* __restrict__ in1,
                                               const unsigned short* __restrict__ B2,
                                               unsigned short* __restrict__ P) {
  __shared__ unsigned short lB[512][36];  // 36.9KB; 72B stride -> worst 2-way bank
  __shared__ float redm[4][32], reds[4][32];

  const int tid = threadIdx.x;
  const int l = tid & 63, w = tid >> 6;
  const int wr = w >> 2, wc = w & 3;      // wave grid 2 x 4
  const int g = l >> 4, c16 = l & 15;
  const int brow = blockIdx.x * 32;

  f32x4 acc[8] = {};

  for (int kt = 0; kt < 16; ++kt) {
    const int k0 = kt * 32;
    // ---- stage B tile [512 cols][32 k] (bf16) ----
#pragma unroll
    for (int i = 0; i < 4; ++i) {
      int c = i * 512 + tid;                // 2048 chunks of 8 shorts
      int col = c >> 2, sub = c & 3;
      *reinterpret_cast<u16x8*>(&lB[col][sub * 8]) =
          *reinterpret_cast<const u16x8*>(B2 + (size_t)col * 512 + k0 + sub * 8);
    }
    // ---- A fragment direct from global, split in-register [r6-validated] ----
    const int arow = brow + wr * 16 + c16;
    float4 v0 = *reinterpret_cast<const float4*>(in1 + (size_t)arow * 512 + k0 + g * 8);
    float4 v1 = *reinterpret_cast<const float4*>(in1 + (size_t)arow * 512 + k0 + g * 8 + 4);
    bf16x8 ahi, alo;
    {
      float vv[8] = {v0.x, v0.y, v0.z, v0.w, v1.x, v1.y, v1.z, v1.w};
      unsigned short h[8], lo8[8];
#pragma unroll
      for (int e = 0; e < 8; ++e) {
        h[e] = f2bf(vv[e]);
        lo8[e] = f2bf(vv[e] - bf2f(h[e]));
      }
      ahi = *reinterpret_cast<const bf16x8*>(h);
      alo = *reinterpret_cast<const bf16x8*>(lo8);
    }
    __syncthreads();
#pragma unroll
    for (int j = 0; j < 8; ++j) {
      const int col = wc * 128 + j * 16 + c16;
      bf16x8 bh = *reinterpret_cast<const bf16x8*>(&lB[col][g * 8]);
      acc[j] = __builtin_amdgcn_mfma_f32_16x16x32_bf16(ahi, bh, acc[j], 0, 0, 0);
      acc[j] = __builtin_amdgcn_mfma_f32_16x16x32_bf16(alo, bh, acc[j], 0, 0, 0);
    }
    __syncthreads();
  }

  // ---- epilogue: scale, softmax over 512 cols, dropout, write P bf16 [r6-validated] ----
  // C/D layout: col = c16 (+j*16+wc*128), row = g*4 + r (+wr*16)
  const int rowbase = wr * 16 + g * 4;
  float mx[4] = {-3.4e38f, -3.4e38f, -3.4e38f, -3.4e38f};
#pragma unroll
  for (int j = 0; j < 8; ++j)
#pragma unroll
    for (int r = 0; r < 4; ++r) {
      acc[j][r] *= SM_SCALE;
      mx[r] = fmaxf(mx[r], acc[j][r]);
    }
#pragma unroll
  for (int s = 1; s < 16; s <<= 1)
#pragma unroll
    for (int r = 0; r < 4; ++r) mx[r] = fmaxf(mx[r], __shfl_xor(mx[r], s, 64));
  if (c16 == 0) {
#pragma unroll
    for (int r = 0; r < 4; ++r) redm[wc][rowbase + r] = mx[r];
  }
  __syncthreads();
  float rmax[4], sum[4] = {0.f, 0.f, 0.f, 0.f};
#pragma unroll
  for (int r = 0; r < 4; ++r)
    rmax[r] = fmaxf(fmaxf(redm[0][rowbase + r], redm[1][rowbase + r]),
                    fmaxf(redm[2][rowbase + r], redm[3][rowbase + r]));
#pragma unroll
  for (int j = 0; j < 8; ++j)
#pragma unroll
    for (int r = 0; r < 4; ++r) {
      float e = expf(acc[j][r] - rmax[r]);
      acc[j][r] = e;
      sum[r] += e;
    }
#pragma unroll
  for (int s = 1; s < 16; s <<= 1)
#pragma unroll
    for (int r = 0; r < 4; ++r) sum[r] += __shfl_xor(sum[r], s, 64);
  if (c16 == 0) {
#pragma unroll
    for (int r = 0; r < 4; ++r) reds[wc][rowbase + r] = sum[r];
  }
  __syncthreads();
  float scl[4];
#pragma unroll
  for (int r = 0; r < 4; ++r)
    scl[r] = DROP_SCALE / (reds[0][rowbase + r] + reds[1][rowbase + r] +
                           reds[2][rowbase + r] + reds[3][rowbase + r]);

#pragma unroll
  for (int j = 0; j < 8; ++j) {
    const int col = wc * 128 + j * 16 + c16;
#pragma unroll
    for (int r = 0; r < 4; ++r) {
      uint32_t idx = (uint32_t)(brow + rowbase + r) * 512u + (uint32_t)col;
      float pv = drop_keep(idx) ? acc[j][r] * scl[r] : 0.0f;
      P[idx] = f2bf(pv);
    }
  }
}

// ---------- kernel 3: out = P[16384][512] @ vT[4096][512]^T (bf16 MFMA) ----------
// [r4 bytes, reg-staged LDS +8 pad — measured 60us, validated]
__global__ __launch_bounds__(256) void k_pv(const unsigned short* __restrict__ P,
                                            const unsigned short* __restrict__ VT,
                                            float* __restrict__ out) {
  __shared__ unsigned short lA[128][72];  // 72 = 64 + 8 pad (16B-aligned rows)
  __shared__ unsigned short lB[128][72];
  const int tid = threadIdx.x;
  const int l = tid & 63, w = tid >> 6;
  const int wr = w >> 1, wc = w & 1;
  const int g = l >> 4, c16 = l & 15;

  // XCD-aware bijective swizzle (4096 % 8 == 0)
  const int bid = blockIdx.x;
  const int x = (bid & 7) * 512 + (bid >> 3);
  const int brow = (x >> 5) * 128;   // 128 row-tiles
  const int bcol = (x & 31) * 128;   // 32 col-tiles

  f32x4 acc[4][4] = {};

  for (int kt = 0; kt < 8; ++kt) {
    const int k0 = kt * 64;
#pragma unroll
    for (int i = 0; i < 4; ++i) {
      int c = i * 256 + tid;          // 0..1023 chunks of 8 shorts
      int row = c >> 3, sub = c & 7;
      u16x8 va = *reinterpret_cast<const u16x8*>(
          P + (size_t)(brow + row) * 512 + k0 + sub * 8);
      u16x8 vb = *reinterpret_cast<const u16x8*>(
          VT + (size_t)(bcol + row) * 512 + k0 + sub * 8);
      *reinterpret_cast<u16x8*>(&lA[row][sub * 8]) = va;
      *reinterpret_cast<u16x8*>(&lB[row][sub * 8]) = vb;
    }
    __syncthreads();

#pragma unroll
    for (int kk = 0; kk < 64; kk += 32) {
      bf16x8 a[4], b[4];
#pragma unroll
      for (int i = 0; i < 4; ++i)
        a[i] = *reinterpret_cast<const bf16x8*>(&lA[wr * 64 + i * 16 + c16][kk + g * 8]);
#pragma unroll
      for (int j = 0; j < 4; ++j)
        b[j] = *reinterpret_cast<const bf16x8*>(&lB[wc * 64 + j * 16 + c16][kk + g * 8]);
#pragma unroll
      for (int i = 0; i < 4; ++i)
#pragma unroll
        for (int j = 0; j < 4; ++j)
          acc[i][j] = __builtin_amdgcn_mfma_f32_16x16x32_bf16(a[i], b[j], acc[i][j], 0, 0, 0);
    }
    __syncthreads();
  }

  // C/D layout (validated r4): col = lane&15, row = (lane>>4)*4 + reg
#pragma unroll
  for (int i = 0; i < 4; ++i)
#pragma unroll
    for (int r = 0; r < 4; ++r) {
      const size_t row = (size_t)(brow + wr * 64 + i * 16 + g * 4 + r);
      float* o = out + row * 4096 + bcol + wc * 64 + c16;
#pragma unroll
      for (int j = 0; j < 4; ++j) o[j * 16] = acc[i][j][r];
    }
}

// ---------- launch ----------
extern "C" void kernel_launch(void* const* d_in, const int* in_sizes, int n_in,
                              void* d_out, int out_size, void* d_ws, size_t ws_size,
                              hipStream_t stream) {
  (void)in_sizes; (void)n_in; (void)out_size; (void)ws_size;
  const float* in1   = (const float*)d_in[0];   // [16384][512]
  const float* in2   = (const float*)d_in[1];   // [512][512]
  const float* value = (const float*)d_in[2];   // [512][4096]
  float* out = (float*)d_out;                   // [16384][4096]

  unsigned short* vT   = (unsigned short*)d_ws;  // 4 MB   [4096][512] bf16
  unsigned short* Pb   = vT + 2097152;           // 16 MB  [16384][512] bf16
  unsigned short* in2b = Pb + 8388608;           // 0.5 MB [512][512] bf16

  k_vt<<<dim3(128, 16), dim3(256), 0, stream>>>(value, vT);
  k_cast<<<dim3(256), dim3(256), 0, stream>>>(in2, in2b, 65536);
  k_qk<<<dim3(512), dim3(512), 0, stream>>>(in1, in2b, Pb);
  k_pv<<<dim3(4096), dim3(256), 0, stream>>>(Pb, vT, out);
}